// Round 1
// baseline (1209.310 us; speedup 1.0000x reference)
//
#include <hip/hip_runtime.h>

// ---------------------------------------------------------------------------
// CIN++ conv, MI355X. Round 2:
//  - x@W_top folded into edge GEMMs (K=256): M_T kernel, T storage and the
//    scalar u16 T-gather epilogue all deleted; x rows gathered with 16B loads
//    that overlap the LDS staging barrier (x is L2/L3-resident)
//  - scat3 writes one packed int4 per edge (perm,src,dst) -> 1 dirty line
//    instead of 3 per edge
//  - bn_params folded into XFORM GEMM prologues and finalize (4 launches gone)
// ---------------------------------------------------------------------------

#define NCELLS 32768
#define EUP    524288
#define EDN    524288
#define EB     131072
#define NS     4194304          // NCELLS * 128
#define CH_SH  17408            // ushorts per transposed W chunk (128*136)

typedef __attribute__((ext_vector_type(8))) __bf16 bf16x8;
typedef __attribute__((ext_vector_type(4))) float  float4v;

static __device__ __forceinline__ unsigned short f2bf(float v) {
  __bf16 b = (__bf16)v;
  return __builtin_bit_cast(unsigned short, b);
}

#define GLD_LDS16(gp, lp)                                                    \
  __builtin_amdgcn_global_load_lds(                                          \
      (const __attribute__((address_space(1))) void*)(gp),                   \
      (__attribute__((address_space(3))) void*)(lp), 16, 0, 0)

enum { M_Z = 0, M_COMB = 1 };

// ---------------------------------------------------------------------------
// Edge message GEMM, K=256: relu(cat[x_src, attr] @ W + b), dst-sorted rows,
// segmented-reduction epilogue with fp32 atomics into h. blockIdx.y: up/down.
// ---------------------------------------------------------------------------
__global__ __launch_bounds__(256) void edge_gemm_k(
    const float* __restrict__ xin,
    const float* __restrict__ upA, const float* __restrict__ dnA,
    const unsigned short* __restrict__ wsT,
    const float* __restrict__ upb, const float* __restrict__ dnb,
    const int4* __restrict__ ue, const int4* __restrict__ de,
    float* __restrict__ hout)
{
  __shared__ __align__(16) unsigned short Wt[CH_SH];   // reused as C[64][132]
  __shared__ int sdst_s[64];

  const int tid  = threadIdx.x;
  const int wave = tid >> 6, lane = tid & 63;
  const int quad = lane >> 4, l16 = lane & 15;
  const int br   = blockIdx.y;

  const float* attr  = br ? dnA : upA;
  const float* bias  = br ? dnb : upb;
  const int4*  edges = br ? de : ue;
  float* outb = hout + (size_t)br * NS;
  const int cbase = 2 * br;                 // W chunks: {0,1} up, {2,3} down

  const int rowBase = blockIdx.x * 64 + wave * 16;
  const int4 e = edges[rowBase + l16];      // (attr_row, src, dst, 0)
  if (quad == 0) sdst_s[wave * 16 + l16] = e.z;

  float4v acc[8];
#pragma unroll
  for (int nt = 0; nt < 8; ++nt) acc[nt] = (float4v){0.f, 0.f, 0.f, 0.f};

#pragma unroll
  for (int kc = 0; kc < 256; kc += 128) {
    // A fragment preload (registers) before the staging barrier:
    //   chunk 0 -> gathered x[src] rows (L2/L3 resident), chunk 1 -> attr rows
    const float* Abase = kc ? attr : xin;
    const int ar = kc ? e.x : e.y;
    float4v pa[4], pb[4];
#pragma unroll
    for (int ks = 0; ks < 4; ++ks) {
      const float* ap = Abase + (size_t)ar * 128 + ks * 32 + quad * 8;
      pa[ks] = *(const float4v*)ap;
      pb[ks] = *(const float4v*)(ap + 4);
    }

    if (kc) __syncthreads();
    {  // async stage: 34816 B of pre-transposed bf16 W into LDS
      const char* g = (const char*)(wsT + (size_t)(cbase + (kc >> 7)) * CH_SH);
      char* l = (char*)Wt;
      for (int off = wave * 1024; off < 2 * CH_SH; off += 4096)
        GLD_LDS16(g + off + lane * 16, l + off);
    }
    __syncthreads();

#pragma unroll
    for (int ks = 0; ks < 4; ++ks) {
      bf16x8 af;
#pragma unroll
      for (int j = 0; j < 4; ++j) {
        af[j]     = (__bf16)pa[ks][j];
        af[4 + j] = (__bf16)pb[ks][j];
      }
#pragma unroll
      for (int nt = 0; nt < 8; ++nt) {
        bf16x8 bf = *(const bf16x8*)&Wt[(nt * 16 + l16) * 136 + ks * 32 + quad * 8];
        acc[nt] = __builtin_amdgcn_mfma_f32_16x16x32_bf16(af, bf, acc[nt], 0, 0, 0);
      }
    }
  }

  __syncthreads();                        // all waves done reading Wt
  float* Cb = (float*)Wt;                 // 64 x 132 fp32 (33792 B <= 34816)
#pragma unroll
  for (int nt = 0; nt < 8; ++nt) {
    const int col = nt * 16 + l16;
    const float bb = bias[col];
#pragma unroll
    for (int r = 0; r < 4; ++r)
      Cb[(wave * 16 + quad * 4 + r) * 132 + col] = fmaxf(acc[nt][r] + bb, 0.f);
  }
  __syncthreads();
  // segmented reduction over dst-sorted rows: ~4-6 distinct dsts per block
  const int col = tid & 127, half = tid >> 7;
  const int r0 = half * 32;
  int cur = sdst_s[r0];
  float a = 0.f;
  for (int r = r0; r < r0 + 32; ++r) {
    int d = sdst_s[r];
    if (d != cur) {
      unsafeAtomicAdd(&outb[(size_t)cur * 128 + col], a);
      a = 0.f; cur = d;
    }
    a += Cb[r * 132 + col];
  }
  unsafeAtomicAdd(&outb[(size_t)cur * 128 + col], a);
}

// ---------------------------------------------------------------------------
// MLP / combine GEMM. XFORM: BN params computed in-prologue from raw stats of
// the previous layer (bn_params kernel eliminated). blockIdx.y = branch (M_Z).
// ---------------------------------------------------------------------------
template<int MODE, bool XFORM>
__global__ __launch_bounds__(256) void mlp_gemm_k(
    const float* __restrict__ A,
    const unsigned short* __restrict__ wsT, int chunk0,
    const float* __restrict__ bias,
    const float* __restrict__ psum, const float* __restrict__ psq,
    const float* __restrict__ pg, const float* __restrict__ pbe,
    float* __restrict__ outp,
    float* __restrict__ ssum, float* __restrict__ ssq, int K)
{
  __shared__ __align__(16) unsigned short Wt[CH_SH];
  __shared__ float sTa[384], sTc[384];

  const int tid  = threadIdx.x;
  const int wave = tid >> 6, lane = tid & 63;
  const int quad = lane >> 4, l16 = lane & 15;
  const int br   = blockIdx.y;

  const float* Ab = A;
  const float* biasb = bias;
  const float* psb = psum; const float* pqb = psq;
  const float* pgb = pg;   const float* pbeb = pbe;
  float* outb = outp;
  float* ssumb = ssum; float* ssqb = ssq;
  int cidx = chunk0;
  if (MODE == M_Z) {
    Ab += (size_t)br * NS; cidx += br; biasb += 128 * br;
    outb += (size_t)br * NS; ssumb += 128 * br; ssqb += 128 * br;
    if (XFORM) { psb += 128 * br; pqb += 128 * br; pgb += 128 * br; pbeb += 128 * br; }
  }

  if (XFORM)
    for (int i = tid; i < K; i += 256) {
      float m   = psb[i] * (1.f / NCELLS);
      float var = pqb[i] * (1.f / NCELLS) - m * m;
      float ai  = pgb[i] * rsqrtf(var + 1e-5f);
      sTa[i] = ai;
      sTc[i] = pbeb[i] - m * ai;
    }

  const int rowBase = blockIdx.x * 64 + wave * 16;
  const int arow = rowBase + l16;

  float4v acc[8];
#pragma unroll
  for (int nt = 0; nt < 8; ++nt) acc[nt] = (float4v){0.f, 0.f, 0.f, 0.f};

  for (int kc = 0; kc < K; kc += 128) {
    float4v pa[4], pb[4];
#pragma unroll
    for (int ks = 0; ks < 4; ++ks) {
      const float* ap;
      if (MODE == M_COMB)
        ap = Ab + (size_t)(kc >> 7) * NS + (size_t)arow * 128 + ks * 32 + quad * 8;
      else
        ap = Ab + (size_t)arow * 128 + ks * 32 + quad * 8;
      pa[ks] = *(const float4v*)ap;
      pb[ks] = *(const float4v*)(ap + 4);
    }

    if (kc) __syncthreads();
    {
      const char* g = (const char*)(wsT + (size_t)(cidx + (kc >> 7)) * CH_SH);
      char* l = (char*)Wt;
      for (int off = wave * 1024; off < 2 * CH_SH; off += 4096)
        GLD_LDS16(g + off + lane * 16, l + off);
    }
    __syncthreads();   // also covers sTa/sTc fill on first iteration

#pragma unroll
    for (int ks = 0; ks < 4; ++ks) {
      const int kk0 = kc + ks * 32 + quad * 8;
      float av[8];
#pragma unroll
      for (int j = 0; j < 4; ++j) { av[j] = pa[ks][j]; av[4 + j] = pb[ks][j]; }
      if (XFORM) {
#pragma unroll
        for (int j = 0; j < 8; ++j)
          av[j] = fmaxf(fmaf(sTa[kk0 + j], av[j], sTc[kk0 + j]), 0.f);
      }
      bf16x8 af;
#pragma unroll
      for (int j = 0; j < 8; ++j) af[j] = (__bf16)av[j];
#pragma unroll
      for (int nt = 0; nt < 8; ++nt) {
        bf16x8 bf = *(const bf16x8*)&Wt[(nt * 16 + l16) * 136 + ks * 32 + quad * 8];
        acc[nt] = __builtin_amdgcn_mfma_f32_16x16x32_bf16(af, bf, acc[nt], 0, 0, 0);
      }
    }
  }

  const int crow = rowBase + quad * 4;     // C frag rows crow..crow+3
#pragma unroll
  for (int nt = 0; nt < 8; ++nt) {
    const int col = nt * 16 + l16;
    const float bb = biasb[col];
    float s = 0.f, ss = 0.f;
#pragma unroll
    for (int r = 0; r < 4; ++r) {
      float v = acc[nt][r] + bb;
      outb[(size_t)(crow + r) * 128 + col] = v;
      s += v; ss += v * v;
    }
    s  += __shfl_xor(s, 16);  s  += __shfl_xor(s, 32);
    ss += __shfl_xor(ss, 16); ss += __shfl_xor(ss, 32);
    if (quad == 0) {
      unsafeAtomicAdd(&ssumb[col], s);
      unsafeAtomicAdd(&ssqb[col], ss);
    }
  }
}

// transpose + bf16-convert all GEMM weights into 13 chunks of [n*136+k]
__global__ __launch_bounds__(256) void prep_w(
    const float* __restrict__ muw, const float* __restrict__ mdw,
    const float* __restrict__ w1, const float* __restrict__ w2,
    const float* __restrict__ cw, unsigned short* __restrict__ wsT)
{
  const int chunk = blockIdx.y;
  const float* src;
  if      (chunk == 0) src = muw;
  else if (chunk == 1) src = muw + 16384;
  else if (chunk == 2) src = mdw;
  else if (chunk == 3) src = mdw + 16384;
  else if (chunk < 7)  src = w1 + (chunk - 4) * 16384;
  else if (chunk < 10) src = w2 + (chunk - 7) * 16384;
  else                 src = cw + (chunk - 10) * 16384;
  int i = blockIdx.x * 256 + threadIdx.x;   // 0..16383
  int k = i >> 7, n = i & 127;
  wsT[(size_t)chunk * CH_SH + n * 136 + k] = f2bf(src[i]);
}

// histogram of dsts for up / down / boundary into 3 x 32768 counters
__global__ __launch_bounds__(256) void hist3(
    const int* __restrict__ up, const int* __restrict__ dn,
    const int* __restrict__ bnd, int* __restrict__ cnts)
{
  int i = blockIdx.x * 256 + threadIdx.x;
  if (i < EUP) atomicAdd(&cnts[up[i]], 1);
  else if (i < EUP + EDN) atomicAdd(&cnts[32768 + dn[i - EUP]], 1);
  else atomicAdd(&cnts[65536 + bnd[EB + (i - EUP - EDN)]], 1);
}

// per-segment exclusive scan (3 x 32768), writes row_start + scatter cursor
__global__ __launch_bounds__(1024) void scan3(
    const int* __restrict__ cnts, int* __restrict__ rs, int* __restrict__ cur)
{
  __shared__ int part[1024];
  const int seg = blockIdx.x, t = threadIdx.x;
  const int* c = cnts + seg * 32768;
  int local[32]; int s = 0;
#pragma unroll
  for (int i = 0; i < 32; ++i) { local[i] = c[t * 32 + i]; s += local[i]; }
  part[t] = s;
  __syncthreads();
  for (int off = 1; off < 1024; off <<= 1) {
    int v = (t >= off) ? part[t - off] : 0;
    __syncthreads();
    part[t] += v;
    __syncthreads();
  }
  int base = t ? part[t - 1] : 0;
  int* r  = rs  + seg * 32769;
  int* cu = cur + seg * 32768;
#pragma unroll
  for (int i = 0; i < 32; ++i) {
    r[t * 32 + i] = base; cu[t * 32 + i] = base; base += local[i];
  }
  if (t == 1023) r[32768] = part[1023];
}

// scatter edges into dst-sorted order; one packed int4 per edge (1 dirty line)
__global__ __launch_bounds__(256) void scat3(
    const int* __restrict__ up, const int* __restrict__ dn,
    const int* __restrict__ bnd, int* __restrict__ cur,
    int4* __restrict__ ue, int4* __restrict__ de, int* __restrict__ bperm)
{
  int i = blockIdx.x * 256 + threadIdx.x;
  if (i < EUP) {
    int d = up[i]; int p = atomicAdd(&cur[d], 1);
    int4 v; v.x = i; v.y = up[EUP + i]; v.z = d; v.w = 0;
    ue[p] = v;
  } else if (i < EUP + EDN) {
    int e = i - EUP; int d = dn[e]; int p = atomicAdd(&cur[32768 + d], 1);
    int4 v; v.x = e; v.y = dn[EDN + e]; v.z = d; v.w = 0;
    de[p] = v;
  } else {
    int e = i - EUP - EDN; int d = bnd[EB + e];
    int p = atomicAdd(&cur[65536 + d], 1);
    bperm[p] = bnd[e];                       // battr row id, sorted by dst
  }
}

// h0 = h1 = x (self term; edge messages atomically added on top)
__global__ __launch_bounds__(256) void init_h01(const float* __restrict__ x,
                                                float* __restrict__ h)
{
  size_t i = (size_t)blockIdx.x * 256 + threadIdx.x;
  float4v v = ((const float4v*)x)[i];
  ((float4v*)h)[i] = v;
  ((float4v*)(h + NS))[i] = v;
}

// h2[n] = x[n] + sum over CSR range of battr rows (no atomics)
__global__ __launch_bounds__(256) void bnd_agg(
    const float* __restrict__ x, const float* __restrict__ battr,
    const int* __restrict__ bperm, const int* __restrict__ rs,
    float* __restrict__ h2)
{
  int node = blockIdx.x * 2 + (threadIdx.x >> 7);
  int col  = threadIdx.x & 127;
  float acc = x[(size_t)node * 128 + col];
  int s = rs[node], e = rs[node + 1];
  for (int i = s; i < e; ++i)
    acc += battr[(size_t)bperm[i] * 128 + col];
  h2[(size_t)node * 128 + col] = acc;
}

// BN params computed inline from comb stats (bn_params kernel eliminated)
__global__ __launch_bounds__(256) void finalize_k(
    const float* __restrict__ z3, const float* __restrict__ ssum,
    const float* __restrict__ ssq, const float* __restrict__ g,
    const float* __restrict__ be, float* __restrict__ out)
{
  int idx = blockIdx.x * 256 + threadIdx.x;
  int ch = idx & 127;
  float m   = ssum[ch] * (1.f / NCELLS);
  float var = ssq[ch] * (1.f / NCELLS) - m * m;
  float a   = g[ch] * rsqrtf(var + 1e-5f);
  float c   = be[ch] - m * a;
  out[idx] = fmaxf(fmaf(a, z3[idx], c), 0.f);
}

extern "C" void kernel_launch(void* const* d_in, const int* in_sizes, int n_in,
                              void* d_out, int out_size, void* d_ws, size_t ws_size,
                              hipStream_t stream)
{
  (void)in_sizes; (void)n_in; (void)out_size; (void)ws_size;

  const float* x       = (const float*)d_in[0];
  const int*   up_idx  = (const int*)d_in[1];
  const int*   dn_idx  = (const int*)d_in[2];
  const int*   b_idx   = (const int*)d_in[3];
  const float* up_attr = (const float*)d_in[4];
  const float* dn_attr = (const float*)d_in[5];
  const float* b_attr  = (const float*)d_in[6];
  const float* mu_w    = (const float*)d_in[7];
  const float* mu_b    = (const float*)d_in[8];
  const float* md_w    = (const float*)d_in[9];
  const float* md_b    = (const float*)d_in[10];
  const float* w1      = (const float*)d_in[11];
  const float* b1      = (const float*)d_in[12];
  const float* g1      = (const float*)d_in[13];
  const float* be1     = (const float*)d_in[14];
  const float* w2      = (const float*)d_in[15];
  const float* b2      = (const float*)d_in[16];
  const float* g2      = (const float*)d_in[17];
  const float* be2     = (const float*)d_in[18];
  const float* cw      = (const float*)d_in[19];
  const float* cb      = (const float*)d_in[20];
  const float* cg      = (const float*)d_in[21];
  const float* cbe     = (const float*)d_in[22];

  // ---- workspace layout (z2 aliases h, z3 aliases z1 -> ~119 MB peak)
  float* ws = (float*)d_ws;
  float* h     = ws;                                // 3 x NS  (also z2)
  float* z1    = h + 3 * (size_t)NS;                // 3 x NS  (also z3)
  float* z2    = h;
  float* z3    = z1;
  float* stats = z1 + 3 * (size_t)NS;               // 1792
  unsigned short* wsT = (unsigned short*)(stats + 1792);  // 13 * 17408 ushorts
  int* cnts  = (int*)(wsT + 13 * (size_t)CH_SH);    // 3 x 32768
  int* cur   = cnts + 3 * 32768;
  int* rs    = cur + 3 * 32768;                     // 3 x 32769 (+1 pad)
  int4* ue   = (int4*)(rs + 3 * 32769 + 1);         // 16B-aligned
  int4* de   = ue + EUP;
  int* bperm = (int*)(de + EDN);

  hipMemsetAsync(stats, 0, 1792 * sizeof(float), stream);
  hipMemsetAsync(cnts, 0, 3 * 32768 * sizeof(int), stream);

  prep_w<<<dim3(64, 13), 256, 0, stream>>>(mu_w, md_w, w1, w2, cw, wsT);
  hist3<<<4608, 256, 0, stream>>>(up_idx, dn_idx, b_idx, cnts);
  scan3<<<3, 1024, 0, stream>>>(cnts, rs, cur);
  scat3<<<4608, 256, 0, stream>>>(up_idx, dn_idx, b_idx, cur, ue, de, bperm);

  init_h01<<<4096, 256, 0, stream>>>(x, h);

  // fused edge GEMMs (K=256: x half + attr half), up & down batched
  edge_gemm_k<<<dim3(8192, 2), 256, 0, stream>>>(
      x, up_attr, dn_attr, wsT, mu_b, md_b, ue, de, h);

  bnd_agg<<<16384, 256, 0, stream>>>(x, b_attr, bperm, rs + 2 * 32769,
                                     h + 2 * (size_t)NS);

  // layer 1 (3 branches batched)
  mlp_gemm_k<M_Z, false><<<dim3(512, 3), 256, 0, stream>>>(
      h, wsT, 4, b1, nullptr, nullptr, nullptr, nullptr,
      z1, stats, stats + 384, 128);

  // layer 2 (BN+ReLU of layer 1 computed in-prologue, applied on A-load)
  mlp_gemm_k<M_Z, true><<<dim3(512, 3), 256, 0, stream>>>(
      z1, wsT, 7, b2, stats, stats + 384, g1, be1,
      z2, stats + 768, stats + 1152, 128);

  // combine (K=384 over 3-branch concat)
  mlp_gemm_k<M_COMB, true><<<dim3(512, 1), 256, 0, stream>>>(
      z2, wsT, 10, cb, stats + 768, stats + 1152, g2, be2,
      z3, stats + 1536, stats + 1664, 384);

  finalize_k<<<16384, 256, 0, stream>>>(z3, stats + 1536, stats + 1664,
                                        cg, cbe, (float*)d_out);
}